// Round 1
// baseline (1118.454 us; speedup 1.0000x reference)
//
#include <hip/hip_runtime.h>

// ---------------------------------------------------------------------------
// DbrxAttention on MI355X (gfx950): QKV GEMM -> RoPE -> causal GQA flash attn
// -> out GEMM.  All matmuls in bf16 MFMA (16x16x32), fp32 accumulate.
// ---------------------------------------------------------------------------

#define S_   2048
#define D_   6144
#define H_   48
#define KV_  8
#define HD_  128
#define NQK  8192   // (H + 2*KV) * HD
#define REP  6      // H / KV

typedef __attribute__((ext_vector_type(8))) __bf16 bf16x8;
typedef __attribute__((ext_vector_type(4))) __bf16 bf16x4;
typedef __attribute__((ext_vector_type(4))) float  f32x4;
typedef __attribute__((ext_vector_type(4))) float  float4v;

__device__ __forceinline__ void gl_lds16(const void* g, void* l) {
  __builtin_amdgcn_global_load_lds(
      (const __attribute__((address_space(1))) void*)g,
      (__attribute__((address_space(3))) void*)l, 16, 0, 0);
}

// ---------------- fp32 -> bf16 elementwise convert (vector4) ---------------
__global__ __launch_bounds__(256) void cvt_bf16(const float* __restrict__ in,
                                                __bf16* __restrict__ out, int n4) {
  int stride = gridDim.x * 256;
  for (int i = blockIdx.x * 256 + threadIdx.x; i < n4; i += stride) {
    float4v v = ((const float4v*)in)[i];
    bf16x4 o;
    o[0] = (__bf16)v[0]; o[1] = (__bf16)v[1];
    o[2] = (__bf16)v[2]; o[3] = (__bf16)v[3];
    ((bf16x4*)out)[i] = o;
  }
}

// ------------- fp32 [K][N] -> bf16 [N][K] tiled transpose+convert ----------
__global__ __launch_bounds__(256) void wtrans(const float* __restrict__ src,
                                              __bf16* __restrict__ dst,
                                              int K, int N) {
  __shared__ float t[32][33];
  const int n0 = blockIdx.x * 32, k0 = blockIdx.y * 32;
  const int tx = threadIdx.x, ty = threadIdx.y;  // (32, 8)
#pragma unroll
  for (int r = 0; r < 4; ++r)
    t[ty + r * 8][tx] = src[(size_t)(k0 + ty + r * 8) * N + n0 + tx];
  __syncthreads();
#pragma unroll
  for (int r = 0; r < 4; ++r)
    dst[(size_t)(n0 + ty + r * 8) * K + k0 + tx] = (__bf16)t[tx][ty + r * 8];
}

// --------- C[M][N] f32 = A[M][K] bf16 * BT[N][K] bf16 (both row-major) -----
// 128x128 tile, BK=64, 256 threads = 4 waves (2x2), global_load_lds staging.
__global__ __launch_bounds__(256) void gemm_bt(const __bf16* __restrict__ A,
                                               const __bf16* __restrict__ BT,
                                               float* __restrict__ C,
                                               int M, int N, int K) {
  __shared__ __align__(16) __bf16 As[128 * 64];
  __shared__ __align__(16) __bf16 Bs[128 * 64];
  const int tid = threadIdx.x;
  const int w = tid >> 6, l = tid & 63;
  const int lr = l & 15, lg = l >> 4;
  const int wr = w >> 1, wc = w & 1;
  const int m0 = blockIdx.y * 128, n0 = blockIdx.x * 128;
  f32x4 acc[4][4] = {};
  for (int k0 = 0; k0 < K; k0 += 64) {
#pragma unroll
    for (int i = 0; i < 4; ++i) {
      int t = i * 256 + tid;
      int r = t >> 3, c = (t & 7) * 8;           // both tiles are [128][64]
      gl_lds16(A  + (size_t)(m0 + r) * K + k0 + c, As + (size_t)(i * 256 + w * 64) * 8);
      gl_lds16(BT + (size_t)(n0 + r) * K + k0 + c, Bs + (size_t)(i * 256 + w * 64) * 8);
    }
    __syncthreads();
#pragma unroll
    for (int kk = 0; kk < 2; ++kk) {
      bf16x8 a[4], b[4];
#pragma unroll
      for (int m = 0; m < 4; ++m)
        a[m] = *(const bf16x8*)(As + (wr * 64 + m * 16 + lr) * 64 + kk * 32 + lg * 8);
#pragma unroll
      for (int n = 0; n < 4; ++n)
        b[n] = *(const bf16x8*)(Bs + (wc * 64 + n * 16 + lr) * 64 + kk * 32 + lg * 8);
#pragma unroll
      for (int m = 0; m < 4; ++m)
#pragma unroll
        for (int n = 0; n < 4; ++n)
          acc[m][n] = __builtin_amdgcn_mfma_f32_16x16x32_bf16(a[m], b[n], acc[m][n], 0, 0, 0);
    }
    __syncthreads();
  }
  // C/D layout (m89-verified): col = lane&15, row = (lane>>4)*4 + j
#pragma unroll
  for (int m = 0; m < 4; ++m)
#pragma unroll
    for (int n = 0; n < 4; ++n)
#pragma unroll
      for (int j = 0; j < 4; ++j) {
        int row = m0 + wr * 64 + m * 16 + lg * 4 + j;
        int col = n0 + wc * 64 + n * 16 + lr;
        C[(size_t)row * N + col] = acc[m][n][j];
      }
}

// ------------- RoPE on Q (scaled by 1/sqrt(HD)) and K, fp32 -> bf16 --------
__global__ __launch_bounds__(256) void rope_qk(const float* __restrict__ qkv,
                                               const float* __restrict__ cosT,
                                               const float* __restrict__ sinT,
                                               __bf16* __restrict__ Qo,
                                               __bf16* __restrict__ Ko) {
  const int s = blockIdx.x;
  const float* base = qkv + (size_t)s * NQK;
  const float* ct = cosT + s * HD_;
  const float* st = sinT + s * HD_;
  const float scale = 0.08838834764831845f;  // 1/sqrt(128)
  for (int idx = threadIdx.x; idx < H_ * HD_; idx += 256) {
    int h = idx >> 7, d = idx & 127;
    float x = base[idx];
    float r = (d < 64) ? -base[idx + 64] : base[idx - 64];
    Qo[((size_t)s * H_ + h) * HD_ + d] = (__bf16)((x * ct[d] + r * st[d]) * scale);
  }
  for (int idx = threadIdx.x; idx < KV_ * HD_; idx += 256) {
    int h = idx >> 7, d = idx & 127;
    float x = base[H_ * HD_ + idx];
    float r = (d < 64) ? -base[H_ * HD_ + idx + 64] : base[H_ * HD_ + idx - 64];
    Ko[((size_t)s * KV_ + h) * HD_ + d] = (__bf16)(x * ct[d] + r * st[d]);
  }
}

// -------- V transpose: qkv[s][7168 + h*128 + d] f32 -> Vt[h][d][s] bf16 ----
__global__ __launch_bounds__(256) void v_trans(const float* __restrict__ qkv,
                                               __bf16* __restrict__ Vt) {
  __shared__ float t[32][33];
  const int s0 = blockIdx.x * 32, d0 = blockIdx.y * 32, h = blockIdx.z;
  const int tx = threadIdx.x, ty = threadIdx.y;  // (32, 8)
#pragma unroll
  for (int r = 0; r < 4; ++r)
    t[ty + r * 8][tx] = qkv[(size_t)(s0 + ty + r * 8) * NQK + (H_ + KV_) * HD_ + h * HD_ + d0 + tx];
  __syncthreads();
#pragma unroll
  for (int r = 0; r < 4; ++r)
    Vt[((size_t)h * HD_ + d0 + ty + r * 8) * S_ + s0 + tx] = (__bf16)t[tx][ty + r * 8];
}

// -------------------- causal GQA flash attention ---------------------------
// Grid (S/64, H).  Block 256 = 4 waves, each wave owns 16 q-rows.
// Q pre-scaled.  K tile [64][128] and V^T tile [128][64] staged in LDS.
__global__ __launch_bounds__(256) void attn(const __bf16* __restrict__ Q,
                                            const __bf16* __restrict__ Kb,
                                            const __bf16* __restrict__ Vt,
                                            __bf16* __restrict__ O) {
  __shared__ __align__(16) __bf16 Ks[64 * 128];
  __shared__ __align__(16) __bf16 Vs[128 * 64];
  __shared__ __align__(16) __bf16 Ps[4 * 16 * 64];
  const int qt = blockIdx.x, h = blockIdx.y;
  const int kvh = h / REP;
  const int tid = threadIdx.x, w = tid >> 6, l = tid & 63;
  const int lr = l & 15, lg = l >> 4;
  const int qbase = qt * 64;
  const int qrow = qbase + w * 16;
  bf16x8 qf[4];
#pragma unroll
  for (int kd = 0; kd < 4; ++kd)
    qf[kd] = *(const bf16x8*)(Q + ((size_t)(qrow + lr) * H_ + h) * HD_ + kd * 32 + lg * 8);
  f32x4 o[8] = {};
  float mrow[4], lrow[4];
#pragma unroll
  for (int j = 0; j < 4; ++j) { mrow[j] = -1e30f; lrow[j] = 0.f; }
  const int nkv = qt + 1;
  for (int kt = 0; kt < nkv; ++kt) {
    const int kbase = kt * 64;
#pragma unroll
    for (int i = 0; i < 4; ++i) {
      int t = i * 256 + tid;
      int r = t >> 4, c = (t & 15) * 8;          // K tile [64][128]
      gl_lds16(Kb + ((size_t)(kbase + r) * KV_ + kvh) * HD_ + c,
               Ks + (size_t)(i * 256 + w * 64) * 8);
      int r2 = t >> 3, c2 = (t & 7) * 8;         // V^T tile [128][64]
      gl_lds16(Vt + ((size_t)kvh * HD_ + r2) * S_ + kbase + c2,
               Vs + (size_t)(i * 256 + w * 64) * 8);
    }
    __syncthreads();
    // S = Q K^T  (16 MFMA)
    f32x4 s[4];
#pragma unroll
    for (int n = 0; n < 4; ++n) {
      f32x4 z = {};
#pragma unroll
      for (int kd = 0; kd < 4; ++kd) {
        bf16x8 b = *(const bf16x8*)(Ks + (n * 16 + lr) * 128 + kd * 32 + lg * 8);
        z = __builtin_amdgcn_mfma_f32_16x16x32_bf16(qf[kd], b, z, 0, 0, 0);
      }
      s[n] = z;
    }
    if (kt == qt) {  // only diagonal tile needs the causal mask
#pragma unroll
      for (int n = 0; n < 4; ++n)
#pragma unroll
        for (int j = 0; j < 4; ++j) {
          int qg = qrow + lg * 4 + j;
          int kg = kbase + n * 16 + lr;
          if (kg > qg) s[n][j] = -1e30f;
        }
    }
    // online softmax, row r = lg*4+j lives in the 16 lanes sharing lg
#pragma unroll
    for (int j = 0; j < 4; ++j) {
      float mj = fmaxf(fmaxf(s[0][j], s[1][j]), fmaxf(s[2][j], s[3][j]));
      mj = fmaxf(mj, __shfl_xor(mj, 1));
      mj = fmaxf(mj, __shfl_xor(mj, 2));
      mj = fmaxf(mj, __shfl_xor(mj, 4));
      mj = fmaxf(mj, __shfl_xor(mj, 8));
      float mnew = fmaxf(mrow[j], mj);
      float sc = __expf(mrow[j] - mnew);
      float rs = 0.f;
#pragma unroll
      for (int n = 0; n < 4; ++n) {
        float p = __expf(s[n][j] - mnew);
        s[n][j] = p;
        rs += p;
      }
      rs += __shfl_xor(rs, 1); rs += __shfl_xor(rs, 2);
      rs += __shfl_xor(rs, 4); rs += __shfl_xor(rs, 8);
      lrow[j] = lrow[j] * sc + rs;
      mrow[j] = mnew;
#pragma unroll
      for (int dn = 0; dn < 8; ++dn) o[dn][j] *= sc;
    }
    // P (C-layout) -> per-wave LDS tile [16 q][64 k] -> A-fragments
#pragma unroll
    for (int n = 0; n < 4; ++n)
#pragma unroll
      for (int j = 0; j < 4; ++j)
        Ps[w * 1024 + (lg * 4 + j) * 64 + n * 16 + lr] = (__bf16)s[n][j];
    bf16x8 pa0 = *(const bf16x8*)(Ps + w * 1024 + lr * 64 + lg * 8);
    bf16x8 pa1 = *(const bf16x8*)(Ps + w * 1024 + lr * 64 + 32 + lg * 8);
    // O += P V  (16 MFMA)
#pragma unroll
    for (int dn = 0; dn < 8; ++dn) {
      bf16x8 b0 = *(const bf16x8*)(Vs + (dn * 16 + lr) * 64 + lg * 8);
      o[dn] = __builtin_amdgcn_mfma_f32_16x16x32_bf16(pa0, b0, o[dn], 0, 0, 0);
      bf16x8 b1 = *(const bf16x8*)(Vs + (dn * 16 + lr) * 64 + 32 + lg * 8);
      o[dn] = __builtin_amdgcn_mfma_f32_16x16x32_bf16(pa1, b1, o[dn], 0, 0, 0);
    }
    __syncthreads();
  }
#pragma unroll
  for (int dn = 0; dn < 8; ++dn)
#pragma unroll
    for (int j = 0; j < 4; ++j) {
      int row = qrow + lg * 4 + j;
      int col = h * HD_ + dn * 16 + lr;
      O[(size_t)row * D_ + col] = (__bf16)(o[dn][j] / lrow[j]);
    }
}

// ---------------------------------------------------------------------------
extern "C" void kernel_launch(void* const* d_in, const int* in_sizes, int n_in,
                              void* d_out, int out_size, void* d_ws, size_t ws_size,
                              hipStream_t stream) {
  const float* hidden = (const float*)d_in[0];
  const float* cosT   = (const float*)d_in[1];
  const float* sinT   = (const float*)d_in[2];
  const float* w_qkv  = (const float*)d_in[3];
  const float* w_out  = (const float*)d_in[4];
  float* out = (float*)d_out;
  char* ws = (char*)d_ws;

  // Workspace regions (lifetimes overlap-safe, total 226,492,416 B):
  // R0 [0, 100.7MB): wqkvT bf16 [8192][6144], reused for woutT after gemm1
  // R1: hidden bf16 [2048][6144], reused for attn_out bf16 after gemm1
  // R2: qkv fp32 [2048][8192]
  // R3: q bf16 [2048][48][128], k bf16 [2048][8][128], vT bf16 [8][128][2048]
  __bf16* wT  = (__bf16*)ws;
  __bf16* hb  = (__bf16*)(ws + 100663296);
  float*  qkv = (float*)(ws + 100663296 + 25165824);
  __bf16* q_b = (__bf16*)(ws + 100663296 + 25165824 + 67108864);
  __bf16* k_b = q_b + (size_t)S_ * H_ * HD_;
  __bf16* vt_b = k_b + (size_t)S_ * KV_ * HD_;

  // 1. hidden fp32 -> bf16
  cvt_bf16<<<dim3(2048), dim3(256), 0, stream>>>(hidden, hb, (int)((size_t)S_ * D_ / 4));
  // 2. w_qkv [D][NQK] fp32 -> [NQK][D] bf16
  wtrans<<<dim3(NQK / 32, D_ / 32), dim3(32, 8), 0, stream>>>(w_qkv, wT, D_, NQK);
  // 3. qkv = hidden x w_qkv
  gemm_bt<<<dim3(NQK / 128, S_ / 128), dim3(256), 0, stream>>>(hb, wT, qkv, S_, NQK, D_);
  // 4. RoPE -> q_b (scaled), k_b
  rope_qk<<<dim3(S_), dim3(256), 0, stream>>>(qkv, cosT, sinT, q_b, k_b);
  // 5. V transpose -> vt_b
  v_trans<<<dim3(S_ / 32, HD_ / 32, KV_), dim3(32, 8), 0, stream>>>(qkv, vt_b);
  // 6. w_out [6144][6144] fp32 -> transposed bf16 (reuses R0; gemm1 is done in stream order)
  wtrans<<<dim3(D_ / 32, D_ / 32), dim3(32, 8), 0, stream>>>(w_out, wT, D_, D_);
  // 7. attention -> attn_out bf16 (reuses R1)
  attn<<<dim3(S_ / 64, H_), dim3(256), 0, stream>>>(q_b, k_b, vt_b, hb);
  // 8. out = attn_out x w_out
  gemm_bt<<<dim3(D_ / 128, S_ / 128), dim3(256), 0, stream>>>(hb, wT, out, S_, D_, D_);
}

// Round 3
// 1023.040 us; speedup vs baseline: 1.0933x; 1.0933x over previous
//
#include <hip/hip_runtime.h>

// ---------------------------------------------------------------------------
// DbrxAttention on MI355X (gfx950): QKV GEMM -> RoPE -> causal GQA flash attn
// -> out GEMM.  GEMMs: bf16 MFMA 16x16x32 m97-structure.  Attention: LDS-free
// swapped-QK^T 32x32x16 structure, softmax in registers (exp2 domain).
// ---------------------------------------------------------------------------

#define S_   2048
#define D_   6144
#define H_   48
#define KV_  8
#define HD_  128
#define NQK  8192   // (H + 2*KV) * HD
#define REP  6      // H / KV

typedef __attribute__((ext_vector_type(8)))  __bf16 bf16x8;
typedef __attribute__((ext_vector_type(4)))  __bf16 bf16x4;
typedef __attribute__((ext_vector_type(2)))  __bf16 bf16x2;
typedef __attribute__((ext_vector_type(4)))  float  f32x4;
typedef __attribute__((ext_vector_type(16))) float  f32x16;
typedef __attribute__((ext_vector_type(4)))  float  float4v;

__device__ __forceinline__ void gl_lds16(const void* g, void* l) {
  __builtin_amdgcn_global_load_lds(
      (const __attribute__((address_space(1))) void*)g,
      (__attribute__((address_space(3))) void*)l, 16, 0, 0);
}

__device__ __forceinline__ unsigned pack2(float a, float b) {
  union { bf16x2 v; unsigned u; } x;
  x.v[0] = (__bf16)a; x.v[1] = (__bf16)b;
  return x.u;
}

// ---------------- fp32 -> bf16 elementwise convert (vector4) ---------------
__global__ __launch_bounds__(256) void cvt_bf16(const float* __restrict__ in,
                                                __bf16* __restrict__ out, int n4) {
  int stride = gridDim.x * 256;
  for (int i = blockIdx.x * 256 + threadIdx.x; i < n4; i += stride) {
    float4v v = ((const float4v*)in)[i];
    bf16x4 o;
    o[0] = (__bf16)v[0]; o[1] = (__bf16)v[1];
    o[2] = (__bf16)v[2]; o[3] = (__bf16)v[3];
    ((bf16x4*)out)[i] = o;
  }
}

// ------------- fp32 [K][N] -> bf16 [N][K] tiled transpose+convert ----------
__global__ __launch_bounds__(256) void wtrans(const float* __restrict__ src,
                                              __bf16* __restrict__ dst,
                                              int K, int N) {
  __shared__ float t[32][33];
  const int n0 = blockIdx.x * 32, k0 = blockIdx.y * 32;
  const int tx = threadIdx.x, ty = threadIdx.y;  // (32, 8)
#pragma unroll
  for (int r = 0; r < 4; ++r)
    t[ty + r * 8][tx] = src[(size_t)(k0 + ty + r * 8) * N + n0 + tx];
  __syncthreads();
#pragma unroll
  for (int r = 0; r < 4; ++r)
    dst[(size_t)(n0 + ty + r * 8) * K + k0 + tx] = (__bf16)t[tx][ty + r * 8];
}

// --------- C[M][N] f32 = A[M][K] bf16 * BT[N][K] bf16 (both row-major) -----
// 128x128 tile, BK=64, 256 threads = 4 waves (2x2), global_load_lds staging.
// XCD-chunked blockIdx swizzle (grids are multiples of 8 blocks).
__global__ __launch_bounds__(256) void gemm_bt(const __bf16* __restrict__ A,
                                               const __bf16* __restrict__ BT,
                                               float* __restrict__ C,
                                               int M, int N, int K) {
  __shared__ __align__(16) __bf16 As[128 * 64];
  __shared__ __align__(16) __bf16 Bs[128 * 64];
  const int tid = threadIdx.x;
  const int w = tid >> 6, l = tid & 63;
  const int lr = l & 15, lg = l >> 4;
  const int wr = w >> 1, wc = w & 1;
  const int nwg = gridDim.x * gridDim.y;
  int bid = blockIdx.y * gridDim.x + blockIdx.x;
  bid = (bid & 7) * (nwg >> 3) + (bid >> 3);   // bijective: nwg % 8 == 0
  const int m0 = (bid / gridDim.x) * 128, n0 = (bid % gridDim.x) * 128;
  f32x4 acc[4][4] = {};
  for (int k0 = 0; k0 < K; k0 += 64) {
#pragma unroll
    for (int i = 0; i < 4; ++i) {
      int t = i * 256 + tid;
      int r = t >> 3, c = (t & 7) * 8;           // both tiles are [128][64]
      gl_lds16(A  + (size_t)(m0 + r) * K + k0 + c, As + (size_t)(i * 256 + w * 64) * 8);
      gl_lds16(BT + (size_t)(n0 + r) * K + k0 + c, Bs + (size_t)(i * 256 + w * 64) * 8);
    }
    __syncthreads();
#pragma unroll
    for (int kk = 0; kk < 2; ++kk) {
      bf16x8 a[4], b[4];
#pragma unroll
      for (int m = 0; m < 4; ++m)
        a[m] = *(const bf16x8*)(As + (wr * 64 + m * 16 + lr) * 64 + kk * 32 + lg * 8);
#pragma unroll
      for (int n = 0; n < 4; ++n)
        b[n] = *(const bf16x8*)(Bs + (wc * 64 + n * 16 + lr) * 64 + kk * 32 + lg * 8);
#pragma unroll
      for (int m = 0; m < 4; ++m)
#pragma unroll
        for (int n = 0; n < 4; ++n)
          acc[m][n] = __builtin_amdgcn_mfma_f32_16x16x32_bf16(a[m], b[n], acc[m][n], 0, 0, 0);
    }
    __syncthreads();
  }
  // C/D layout (m89-verified): col = lane&15, row = (lane>>4)*4 + j
#pragma unroll
  for (int m = 0; m < 4; ++m)
#pragma unroll
    for (int n = 0; n < 4; ++n)
#pragma unroll
      for (int j = 0; j < 4; ++j) {
        int row = m0 + wr * 64 + m * 16 + lg * 4 + j;
        int col = n0 + wc * 64 + n * 16 + lr;
        C[(size_t)row * N + col] = acc[m][n][j];
      }
}

// ------ RoPE on Q (scaled by log2(e)/sqrt(HD)) and K, fp32 -> bf16 ---------
// Q scale includes log2(e): attention softmax runs in exp2 domain.
__global__ __launch_bounds__(256) void rope_qk(const float* __restrict__ qkv,
                                               const float* __restrict__ cosT,
                                               const float* __restrict__ sinT,
                                               __bf16* __restrict__ Qo,
                                               __bf16* __restrict__ Ko) {
  const int s = blockIdx.x;
  const float* base = qkv + (size_t)s * NQK;
  const float* ct = cosT + s * HD_;
  const float* st = sinT + s * HD_;
  const float scale = 0.1275174313f;  // (1/sqrt(128)) * log2(e)
  for (int idx = threadIdx.x; idx < H_ * HD_; idx += 256) {
    int h = idx >> 7, d = idx & 127;
    float x = base[idx];
    float r = (d < 64) ? -base[idx + 64] : base[idx - 64];
    Qo[((size_t)s * H_ + h) * HD_ + d] = (__bf16)((x * ct[d] + r * st[d]) * scale);
  }
  for (int idx = threadIdx.x; idx < KV_ * HD_; idx += 256) {
    int h = idx >> 7, d = idx & 127;
    float x = base[H_ * HD_ + idx];
    float r = (d < 64) ? -base[H_ * HD_ + idx + 64] : base[H_ * HD_ + idx - 64];
    Ko[((size_t)s * KV_ + h) * HD_ + d] = (__bf16)(x * ct[d] + r * st[d]);
  }
}

// -------- V transpose: qkv[s][7168 + h*128 + d] f32 -> Vt[h][d][s] bf16 ----
__global__ __launch_bounds__(256) void v_trans(const float* __restrict__ qkv,
                                               __bf16* __restrict__ Vt) {
  __shared__ float t[32][33];
  const int s0 = blockIdx.x * 32, d0 = blockIdx.y * 32, h = blockIdx.z;
  const int tx = threadIdx.x, ty = threadIdx.y;  // (32, 8)
#pragma unroll
  for (int r = 0; r < 4; ++r)
    t[ty + r * 8][tx] = qkv[(size_t)(s0 + ty + r * 8) * NQK + (H_ + KV_) * HD_ + h * HD_ + d0 + tx];
  __syncthreads();
#pragma unroll
  for (int r = 0; r < 4; ++r)
    Vt[((size_t)h * HD_ + d0 + ty + r * 8) * S_ + s0 + tx] = (__bf16)t[tx][ty + r * 8];
}

// -------------------- causal GQA flash attention (LDS-free) ----------------
// Grid (S/32, H), block = 64 (one wave owns 32 q-rows of one head).
// Swapped QK^T: S^T[k][q] = mfma(A=K, B=Q)  ->  lane (c=l&31, g=l>>5) holds
// S[k = n*32 + (reg&3) + 8*(reg>>2) + 4g][q = c].  Row (q) softmax is in-lane
// over 32 values + one shfl_xor(32) combine with the partner lane.
// PV computes O^T[d][q] = mfma(A=V^T, B=P); the P B-fragment needs
// P[k = s*16 + g*8 + i][q = c]: own lane holds k === 4g..4g+3 (mod 8), the
// partner (l^32) holds the other half -> 2 packed-u32 shfl_xor(32) per (n,t).
__global__ __launch_bounds__(64, 2) void attn(const __bf16* __restrict__ Q,
                                              const __bf16* __restrict__ Kb,
                                              const __bf16* __restrict__ Vt,
                                              __bf16* __restrict__ O) {
  const int qt = blockIdx.x, h = blockIdx.y, kvh = h / REP;
  const int l = threadIdx.x;
  const int c = l & 31, g = l >> 5;
  const int qrow = qt * 32 + c;
  // Q fragment (B-operand): lane provides Q[q=c][hd = st*16 + g*8 + i]
  bf16x8 qf[8];
  const __bf16* qp = Q + ((size_t)qrow * H_ + h) * HD_ + g * 8;
#pragma unroll
  for (int st = 0; st < 8; ++st) qf[st] = *(const bf16x8*)(qp + st * 16);
  f32x16 o[4] = {};
  float m = -1e30f, lsum = 0.f;
  const int nkv = (qt >> 1) + 1;
  for (int kt = 0; kt < nkv; ++kt) {
    const int kbase = kt * 64;
    // K fragments (A-operand): lane row = k-row = n*32 + c, elems = hd slice
    bf16x8 kf[2][8];
#pragma unroll
    for (int st = 0; st < 8; ++st)
#pragma unroll
      for (int n = 0; n < 2; ++n)
        kf[n][st] = *(const bf16x8*)(Kb + ((size_t)(kbase + n * 32 + c) * KV_ + kvh) * HD_
                                     + st * 16 + g * 8);
    f32x16 s0 = {}, s1 = {};
    __builtin_amdgcn_s_setprio(1);
#pragma unroll
    for (int st = 0; st < 8; ++st) {
      s0 = __builtin_amdgcn_mfma_f32_32x32x16_bf16(kf[0][st], qf[st], s0, 0, 0, 0);
      s1 = __builtin_amdgcn_mfma_f32_32x32x16_bf16(kf[1][st], qf[st], s1, 0, 0, 0);
    }
    __builtin_amdgcn_s_setprio(0);
    // V^T fragments (A-operand for PV): row = d = db*32 + c, elems = kv slice.
    // Issued before softmax so L2 latency hides under the VALU work.
    bf16x8 vf[4][4];
#pragma unroll
    for (int db = 0; db < 4; ++db)
#pragma unroll
      for (int s = 0; s < 4; ++s)
        vf[db][s] = *(const bf16x8*)(Vt + ((size_t)(kvh * HD_ + db * 32 + c)) * S_
                                     + kbase + s * 16 + g * 8);
    if (kt == nkv - 1) {  // only the last tile can cross the causal diagonal
#pragma unroll
      for (int r = 0; r < 16; ++r) {
        int krow = (r & 3) + 8 * (r >> 2) + 4 * g;
        if (kbase + krow > qrow)      s0[r] = -1e30f;
        if (kbase + 32 + krow > qrow) s1[r] = -1e30f;
      }
    }
    // online softmax (exp2 domain), state per lane (uniform for the lane's q)
    float mj = s0[0];
#pragma unroll
    for (int r = 1; r < 16; ++r) mj = fmaxf(mj, s0[r]);
#pragma unroll
    for (int r = 0; r < 16; ++r) mj = fmaxf(mj, s1[r]);
    mj = fmaxf(mj, __shfl_xor(mj, 32));
    float mnew = fmaxf(m, mj);
    float sc = __builtin_amdgcn_exp2f(m - mnew);
    float rs = 0.f;
    float p0[16], p1[16];
#pragma unroll
    for (int r = 0; r < 16; ++r) { p0[r] = __builtin_amdgcn_exp2f(s0[r] - mnew); rs += p0[r]; }
#pragma unroll
    for (int r = 0; r < 16; ++r) { p1[r] = __builtin_amdgcn_exp2f(s1[r] - mnew); rs += p1[r]; }
    rs += __shfl_xor(rs, 32);
    lsum = lsum * sc + rs;
    m = mnew;
#pragma unroll
    for (int db = 0; db < 4; ++db)
#pragma unroll
      for (int r = 0; r < 16; ++r) o[db][r] *= sc;
    // pack P -> bf16, exchange halves with partner lane, build B-fragments
    unsigned bq[4][4];
#pragma unroll
    for (int n = 0; n < 2; ++n)
#pragma unroll
      for (int t = 0; t < 2; ++t) {
        const float* pp = n ? p1 : p0;
        unsigned q0 = pack2(pp[8 * t + 0], pp[8 * t + 1]);
        unsigned q1 = pack2(pp[8 * t + 2], pp[8 * t + 3]);
        unsigned q2 = pack2(pp[8 * t + 4], pp[8 * t + 5]);
        unsigned q3 = pack2(pp[8 * t + 6], pp[8 * t + 7]);
        unsigned v0 = g ? q0 : q2;          // send what the partner needs
        unsigned v1 = g ? q1 : q3;
        unsigned sh0 = (unsigned)__shfl_xor((int)v0, 32);
        unsigned sh1 = (unsigned)__shfl_xor((int)v1, 32);
        int s = n * 2 + t;
        bq[s][0] = g ? sh0 : q0;
        bq[s][1] = g ? sh1 : q1;
        bq[s][2] = g ? q2 : sh0;
        bq[s][3] = g ? q3 : sh1;
      }
    __builtin_amdgcn_s_setprio(1);
#pragma unroll
    for (int s = 0; s < 4; ++s) {
      union { unsigned u[4]; bf16x8 v; } bb;
      bb.u[0] = bq[s][0]; bb.u[1] = bq[s][1]; bb.u[2] = bq[s][2]; bb.u[3] = bq[s][3];
#pragma unroll
      for (int db = 0; db < 4; ++db)
        o[db] = __builtin_amdgcn_mfma_f32_32x32x16_bf16(vf[db][s], bb.v, o[db], 0, 0, 0);
    }
    __builtin_amdgcn_s_setprio(0);
  }
  // store O^T[d][q=c] -> O[qrow][h*128 + d], d = db*32 + 8*rg + 4g + j
  float inv = 1.f / lsum;
#pragma unroll
  for (int db = 0; db < 4; ++db)
#pragma unroll
    for (int rg = 0; rg < 4; ++rg) {
      bf16x4 ov;
#pragma unroll
      for (int j = 0; j < 4; ++j) ov[j] = (__bf16)(o[db][rg * 4 + j] * inv);
      *(bf16x4*)(O + (size_t)qrow * D_ + h * HD_ + db * 32 + rg * 8 + g * 4) = ov;
    }
}

// ---------------------------------------------------------------------------
extern "C" void kernel_launch(void* const* d_in, const int* in_sizes, int n_in,
                              void* d_out, int out_size, void* d_ws, size_t ws_size,
                              hipStream_t stream) {
  const float* hidden = (const float*)d_in[0];
  const float* cosT   = (const float*)d_in[1];
  const float* sinT   = (const float*)d_in[2];
  const float* w_qkv  = (const float*)d_in[3];
  const float* w_out  = (const float*)d_in[4];
  float* out = (float*)d_out;
  char* ws = (char*)d_ws;

  // Workspace regions:
  // R0 [0, 100.7MB): wqkvT bf16 [8192][6144], reused for woutT after gemm1
  // R1: hidden bf16 [2048][6144], reused for attn_out bf16 after gemm1
  // R2: qkv fp32 [2048][8192]
  // R3: q bf16 [2048][48][128], k bf16 [2048][8][128], vT bf16 [8][128][2048]
  __bf16* wT  = (__bf16*)ws;
  __bf16* hb  = (__bf16*)(ws + 100663296);
  float*  qkv = (float*)(ws + 100663296 + 25165824);
  __bf16* q_b = (__bf16*)(ws + 100663296 + 25165824 + 67108864);
  __bf16* k_b = q_b + (size_t)S_ * H_ * HD_;
  __bf16* vt_b = k_b + (size_t)S_ * KV_ * HD_;

  // 1. hidden fp32 -> bf16
  cvt_bf16<<<dim3(2048), dim3(256), 0, stream>>>(hidden, hb, (int)((size_t)S_ * D_ / 4));
  // 2. w_qkv [D][NQK] fp32 -> [NQK][D] bf16
  wtrans<<<dim3(NQK / 32, D_ / 32), dim3(32, 8), 0, stream>>>(w_qkv, wT, D_, NQK);
  // 3. qkv = hidden x w_qkv
  gemm_bt<<<dim3(NQK / 128, S_ / 128), dim3(256), 0, stream>>>(hb, wT, qkv, S_, NQK, D_);
  // 4. RoPE -> q_b (scaled by log2e/sqrt(hd)), k_b
  rope_qk<<<dim3(S_), dim3(256), 0, stream>>>(qkv, cosT, sinT, q_b, k_b);
  // 5. V transpose -> vt_b
  v_trans<<<dim3(S_ / 32, HD_ / 32, KV_), dim3(32, 8), 0, stream>>>(qkv, vt_b);
  // 6. w_out [6144][6144] fp32 -> transposed bf16 (reuses R0)
  wtrans<<<dim3(D_ / 32, D_ / 32), dim3(32, 8), 0, stream>>>(w_out, wT, D_, D_);
  // 7. attention -> attn_out bf16 (reuses R1)
  attn<<<dim3(S_ / 32, H_), dim3(64), 0, stream>>>(q_b, k_b, vt_b, hb);
  // 8. out = attn_out x w_out
  gemm_bt<<<dim3(D_ / 128, S_ / 128), dim3(256), 0, stream>>>(hb, wT, out, S_, D_, D_);
}

// Round 4
// 990.267 us; speedup vs baseline: 1.1294x; 1.0331x over previous
//
#include <hip/hip_runtime.h>

// ---------------------------------------------------------------------------
// DbrxAttention on MI355X (gfx950): QKV GEMM -> RoPE -> causal GQA flash attn
// -> out GEMM.  GEMMs: 256x256 tile, BK=32, 4-slot LDS ring, counted vmcnt,
// raw s_barrier, 32x32x16 MFMA, chunk-XOR LDS swizzle.  Attention: LDS-free
// swapped-QK^T 32x32x16, softmax in registers (exp2 domain).
// ---------------------------------------------------------------------------

#define S_   2048
#define D_   6144
#define H_   48
#define KV_  8
#define HD_  128
#define NQK  8192   // (H + 2*KV) * HD
#define REP  6      // H / KV

typedef __attribute__((ext_vector_type(8)))  __bf16 bf16x8;
typedef __attribute__((ext_vector_type(4)))  __bf16 bf16x4;
typedef __attribute__((ext_vector_type(2)))  __bf16 bf16x2;
typedef __attribute__((ext_vector_type(4)))  float  f32x4;
typedef __attribute__((ext_vector_type(16))) float  f32x16;
typedef __attribute__((ext_vector_type(4)))  float  float4v;

__device__ __forceinline__ void gl_lds16(const void* g, void* l) {
  __builtin_amdgcn_global_load_lds(
      (const __attribute__((address_space(1))) void*)g,
      (__attribute__((address_space(3))) void*)l, 16, 0, 0);
}

__device__ __forceinline__ unsigned pack2(float a, float b) {
  union { bf16x2 v; unsigned u; } x;
  x.v[0] = (__bf16)a; x.v[1] = (__bf16)b;
  return x.u;
}

// ---------------- fp32 -> bf16 elementwise convert (vector4) ---------------
__global__ __launch_bounds__(256) void cvt_bf16(const float* __restrict__ in,
                                                __bf16* __restrict__ out, int n4) {
  int stride = gridDim.x * 256;
  for (int i = blockIdx.x * 256 + threadIdx.x; i < n4; i += stride) {
    float4v v = ((const float4v*)in)[i];
    bf16x4 o;
    o[0] = (__bf16)v[0]; o[1] = (__bf16)v[1];
    o[2] = (__bf16)v[2]; o[3] = (__bf16)v[3];
    ((bf16x4*)out)[i] = o;
  }
}

// ------------- fp32 [K][N] -> bf16 [N][K] tiled transpose+convert ----------
__global__ __launch_bounds__(256) void wtrans(const float* __restrict__ src,
                                              __bf16* __restrict__ dst,
                                              int K, int N) {
  __shared__ float t[32][33];
  const int n0 = blockIdx.x * 32, k0 = blockIdx.y * 32;
  const int tx = threadIdx.x, ty = threadIdx.y;  // (32, 8)
#pragma unroll
  for (int r = 0; r < 4; ++r)
    t[ty + r * 8][tx] = src[(size_t)(k0 + ty + r * 8) * N + n0 + tx];
  __syncthreads();
#pragma unroll
  for (int r = 0; r < 4; ++r)
    dst[(size_t)(n0 + ty + r * 8) * K + k0 + tx] = (__bf16)t[tx][ty + r * 8];
}

// --------- C[M][N] f32 = A[M][K] bf16 * BT[N][K] bf16 (both row-major) -----
// 256x256 tile, BK=32, 512 threads = 8 waves (2M x 4N), per-wave 128x64.
// 4-slot LDS ring: iter kt computes buf[kt&3], stages kt+3 -> buf[(kt+3)&3].
// Counted vmcnt(8) + raw s_barrier per K-tile (loads stay in flight across
// barriers).  32x32x16 MFMA.  Chunk-XOR swizzle (c8 ^ (row>>1)&3) on both
// the pre-swizzled global source and the fragment reads (rule #21).
__global__ __launch_bounds__(512, 2) void gemm_bt(const __bf16* __restrict__ A,
                                                  const __bf16* __restrict__ BT,
                                                  float* __restrict__ C,
                                                  int M, int N, int K) {
  __shared__ __align__(16) __bf16 As[4][256 * 32];
  __shared__ __align__(16) __bf16 Bs[4][256 * 32];
  const int tid = threadIdx.x;
  const int w = tid >> 6, l = tid & 63;
  const int r5 = l & 31, hi = l >> 5;
  const int sx = (r5 >> 1) & 3;               // read-side swizzle key
  const int wm = w >> 2, wn = w & 3;
  const int nwg = gridDim.x * gridDim.y;
  int bid = blockIdx.y * gridDim.x + blockIdx.x;
  bid = (bid & 7) * (nwg >> 3) + (bid >> 3);  // bijective: nwg % 8 == 0
  const int m0 = (bid / gridDim.x) * 256, n0 = (bid % gridDim.x) * 256;
  const int nkt = K >> 5;

  // stage tile kt into ring slot kt&3 (4 x global_load_lds_dwordx4 / thread)
  auto stage = [&](int kt) {
    const int buf = kt & 3;
    const int k0 = kt << 5;
#pragma unroll
    for (int i = 0; i < 2; ++i) {
      int idx = i * 512 + tid;
      int row = idx >> 2, c8 = idx & 3;
      int sc8 = c8 ^ ((row >> 1) & 3);        // pre-swizzled source chunk
      gl_lds16(A  + (size_t)(m0 + row) * K + k0 + sc8 * 8, &As[buf][idx * 8]);
      gl_lds16(BT + (size_t)(n0 + row) * K + k0 + sc8 * 8, &Bs[buf][idx * 8]);
    }
  };

  f32x16 acc[4][2] = {};
  stage(0); stage(1); stage(2);               // 12 loads in flight
  asm volatile("s_waitcnt vmcnt(8)" ::: "memory");  // tile 0 landed
  __builtin_amdgcn_s_barrier();

  for (int kt = 0; kt < nkt; ++kt) {
    if (kt + 3 < nkt) stage(kt + 3);
    const __bf16* __restrict__ Ab = As[kt & 3];
    const __bf16* __restrict__ Bb = Bs[kt & 3];
    bf16x8 af[2][4], bf[2][2];
#pragma unroll
    for (int ks = 0; ks < 2; ++ks) {
#pragma unroll
      for (int m = 0; m < 4; ++m)
        af[ks][m] = *(const bf16x8*)(Ab + (size_t)(wm * 128 + m * 32 + r5) * 32
                                     + (((ks * 2 + hi) ^ sx) * 8));
#pragma unroll
      for (int n = 0; n < 2; ++n)
        bf[ks][n] = *(const bf16x8*)(Bb + (size_t)(wn * 64 + n * 32 + r5) * 32
                                     + (((ks * 2 + hi) ^ sx) * 8));
    }
    __builtin_amdgcn_s_setprio(1);
#pragma unroll
    for (int ks = 0; ks < 2; ++ks)
#pragma unroll
      for (int m = 0; m < 4; ++m)
#pragma unroll
        for (int n = 0; n < 2; ++n)
          acc[m][n] = __builtin_amdgcn_mfma_f32_32x32x16_bf16(af[ks][m], bf[ks][n],
                                                              acc[m][n], 0, 0, 0);
    __builtin_amdgcn_s_setprio(0);
    if (kt + 1 < nkt) {
      if (kt + 3 < nkt)       asm volatile("s_waitcnt vmcnt(8)" ::: "memory");
      else if (kt + 3 == nkt) asm volatile("s_waitcnt vmcnt(4)" ::: "memory");
      else                    asm volatile("s_waitcnt vmcnt(0)" ::: "memory");
      __builtin_amdgcn_s_barrier();
    }
  }
  // C/D layout (m74/m101-verified): col = l&31, row = (r&3) + 8*(r>>2) + 4*hi
#pragma unroll
  for (int m = 0; m < 4; ++m)
#pragma unroll
    for (int n = 0; n < 2; ++n)
#pragma unroll
      for (int r = 0; r < 16; ++r) {
        int row = m0 + wm * 128 + m * 32 + (r & 3) + 8 * (r >> 2) + 4 * hi;
        int col = n0 + wn * 64 + n * 32 + r5;
        C[(size_t)row * N + col] = acc[m][n][r];
      }
}

// ------ RoPE on Q (scaled by log2(e)/sqrt(HD)) and K, fp32 -> bf16 ---------
__global__ __launch_bounds__(256) void rope_qk(const float* __restrict__ qkv,
                                               const float* __restrict__ cosT,
                                               const float* __restrict__ sinT,
                                               __bf16* __restrict__ Qo,
                                               __bf16* __restrict__ Ko) {
  const int s = blockIdx.x;
  const float* base = qkv + (size_t)s * NQK;
  const float* ct = cosT + s * HD_;
  const float* st = sinT + s * HD_;
  const float scale = 0.1275174313f;  // (1/sqrt(128)) * log2(e)
  for (int idx = threadIdx.x; idx < H_ * HD_; idx += 256) {
    int h = idx >> 7, d = idx & 127;
    float x = base[idx];
    float r = (d < 64) ? -base[idx + 64] : base[idx - 64];
    Qo[((size_t)s * H_ + h) * HD_ + d] = (__bf16)((x * ct[d] + r * st[d]) * scale);
  }
  for (int idx = threadIdx.x; idx < KV_ * HD_; idx += 256) {
    int h = idx >> 7, d = idx & 127;
    float x = base[H_ * HD_ + idx];
    float r = (d < 64) ? -base[H_ * HD_ + idx + 64] : base[H_ * HD_ + idx - 64];
    Ko[((size_t)s * KV_ + h) * HD_ + d] = (__bf16)(x * ct[d] + r * st[d]);
  }
}

// -------- V transpose: qkv[s][7168 + h*128 + d] f32 -> Vt[h][d][s] bf16 ----
__global__ __launch_bounds__(256) void v_trans(const float* __restrict__ qkv,
                                               __bf16* __restrict__ Vt) {
  __shared__ float t[32][33];
  const int s0 = blockIdx.x * 32, d0 = blockIdx.y * 32, h = blockIdx.z;
  const int tx = threadIdx.x, ty = threadIdx.y;  // (32, 8)
#pragma unroll
  for (int r = 0; r < 4; ++r)
    t[ty + r * 8][tx] = qkv[(size_t)(s0 + ty + r * 8) * NQK + (H_ + KV_) * HD_ + h * HD_ + d0 + tx];
  __syncthreads();
#pragma unroll
  for (int r = 0; r < 4; ++r)
    Vt[((size_t)h * HD_ + d0 + ty + r * 8) * S_ + s0 + tx] = (__bf16)t[tx][ty + r * 8];
}

// -------------------- causal GQA flash attention (LDS-free) ----------------
// Grid (S/32, H), block = 64 (one wave owns 32 q-rows of one head).
// Swapped QK^T: S^T[k][q] = mfma(A=K, B=Q); softmax in-lane + shfl_xor(32);
// PV: O^T[d][q] = mfma(A=V^T, B=P) with P exchanged via packed shfl_xor(32).
__global__ __launch_bounds__(64, 2) void attn(const __bf16* __restrict__ Q,
                                              const __bf16* __restrict__ Kb,
                                              const __bf16* __restrict__ Vt,
                                              __bf16* __restrict__ O) {
  const int qt = blockIdx.x, h = blockIdx.y, kvh = h / REP;
  const int l = threadIdx.x;
  const int c = l & 31, g = l >> 5;
  const int qrow = qt * 32 + c;
  bf16x8 qf[8];
  const __bf16* qp = Q + ((size_t)qrow * H_ + h) * HD_ + g * 8;
#pragma unroll
  for (int st = 0; st < 8; ++st) qf[st] = *(const bf16x8*)(qp + st * 16);
  f32x16 o[4] = {};
  float m = -1e30f, lsum = 0.f;
  const int nkv = (qt >> 1) + 1;
  for (int kt = 0; kt < nkv; ++kt) {
    const int kbase = kt * 64;
    bf16x8 kf[2][8];
#pragma unroll
    for (int st = 0; st < 8; ++st)
#pragma unroll
      for (int n = 0; n < 2; ++n)
        kf[n][st] = *(const bf16x8*)(Kb + ((size_t)(kbase + n * 32 + c) * KV_ + kvh) * HD_
                                     + st * 16 + g * 8);
    f32x16 s0 = {}, s1 = {};
    __builtin_amdgcn_s_setprio(1);
#pragma unroll
    for (int st = 0; st < 8; ++st) {
      s0 = __builtin_amdgcn_mfma_f32_32x32x16_bf16(kf[0][st], qf[st], s0, 0, 0, 0);
      s1 = __builtin_amdgcn_mfma_f32_32x32x16_bf16(kf[1][st], qf[st], s1, 0, 0, 0);
    }
    __builtin_amdgcn_s_setprio(0);
    bf16x8 vf[4][4];
#pragma unroll
    for (int db = 0; db < 4; ++db)
#pragma unroll
      for (int s = 0; s < 4; ++s)
        vf[db][s] = *(const bf16x8*)(Vt + ((size_t)(kvh * HD_ + db * 32 + c)) * S_
                                     + kbase + s * 16 + g * 8);
    if (kt == nkv - 1) {
#pragma unroll
      for (int r = 0; r < 16; ++r) {
        int krow = (r & 3) + 8 * (r >> 2) + 4 * g;
        if (kbase + krow > qrow)      s0[r] = -1e30f;
        if (kbase + 32 + krow > qrow) s1[r] = -1e30f;
      }
    }
    float mj = s0[0];
#pragma unroll
    for (int r = 1; r < 16; ++r) mj = fmaxf(mj, s0[r]);
#pragma unroll
    for (int r = 0; r < 16; ++r) mj = fmaxf(mj, s1[r]);
    mj = fmaxf(mj, __shfl_xor(mj, 32));
    float mnew = fmaxf(m, mj);
    float sc = __builtin_amdgcn_exp2f(m - mnew);
    float rs = 0.f;
    float p0[16], p1[16];
#pragma unroll
    for (int r = 0; r < 16; ++r) { p0[r] = __builtin_amdgcn_exp2f(s0[r] - mnew); rs += p0[r]; }
#pragma unroll
    for (int r = 0; r < 16; ++r) { p1[r] = __builtin_amdgcn_exp2f(s1[r] - mnew); rs += p1[r]; }
    rs += __shfl_xor(rs, 32);
    lsum = lsum * sc + rs;
    m = mnew;
#pragma unroll
    for (int db = 0; db < 4; ++db)
#pragma unroll
      for (int r = 0; r < 16; ++r) o[db][r] *= sc;
    unsigned bq[4][4];
#pragma unroll
    for (int n = 0; n < 2; ++n)
#pragma unroll
      for (int t = 0; t < 2; ++t) {
        const float* pp = n ? p1 : p0;
        unsigned q0 = pack2(pp[8 * t + 0], pp[8 * t + 1]);
        unsigned q1 = pack2(pp[8 * t + 2], pp[8 * t + 3]);
        unsigned q2 = pack2(pp[8 * t + 4], pp[8 * t + 5]);
        unsigned q3 = pack2(pp[8 * t + 6], pp[8 * t + 7]);
        unsigned v0 = g ? q0 : q2;
        unsigned v1 = g ? q1 : q3;
        unsigned sh0 = (unsigned)__shfl_xor((int)v0, 32);
        unsigned sh1 = (unsigned)__shfl_xor((int)v1, 32);
        int s = n * 2 + t;
        bq[s][0] = g ? sh0 : q0;
        bq[s][1] = g ? sh1 : q1;
        bq[s][2] = g ? q2 : sh0;
        bq[s][3] = g ? q3 : sh1;
      }
    __builtin_amdgcn_s_setprio(1);
#pragma unroll
    for (int s = 0; s < 4; ++s) {
      union { unsigned u[4]; bf16x8 v; } bb;
      bb.u[0] = bq[s][0]; bb.u[1] = bq[s][1]; bb.u[2] = bq[s][2]; bb.u[3] = bq[s][3];
#pragma unroll
      for (int db = 0; db < 4; ++db)
        o[db] = __builtin_amdgcn_mfma_f32_32x32x16_bf16(vf[db][s], bb.v, o[db], 0, 0, 0);
    }
    __builtin_amdgcn_s_setprio(0);
  }
  float inv = 1.f / lsum;
#pragma unroll
  for (int db = 0; db < 4; ++db)
#pragma unroll
    for (int rg = 0; rg < 4; ++rg) {
      bf16x4 ov;
#pragma unroll
      for (int j = 0; j < 4; ++j) ov[j] = (__bf16)(o[db][rg * 4 + j] * inv);
      *(bf16x4*)(O + (size_t)qrow * D_ + h * HD_ + db * 32 + rg * 8 + g * 4) = ov;
    }
}

// ---------------------------------------------------------------------------
extern "C" void kernel_launch(void* const* d_in, const int* in_sizes, int n_in,
                              void* d_out, int out_size, void* d_ws, size_t ws_size,
                              hipStream_t stream) {
  const float* hidden = (const float*)d_in[0];
  const float* cosT   = (const float*)d_in[1];
  const float* sinT   = (const float*)d_in[2];
  const float* w_qkv  = (const float*)d_in[3];
  const float* w_out  = (const float*)d_in[4];
  float* out = (float*)d_out;
  char* ws = (char*)d_ws;

  // Workspace regions:
  // R0 [0, 100.7MB): wqkvT bf16 [8192][6144], reused for woutT after gemm1
  // R1: hidden bf16 [2048][6144], reused for attn_out bf16 after gemm1
  // R2: qkv fp32 [2048][8192]
  // R3: q bf16 [2048][48][128], k bf16 [2048][8][128], vT bf16 [8][128][2048]
  __bf16* wT  = (__bf16*)ws;
  __bf16* hb  = (__bf16*)(ws + 100663296);
  float*  qkv = (float*)(ws + 100663296 + 25165824);
  __bf16* q_b = (__bf16*)(ws + 100663296 + 25165824 + 67108864);
  __bf16* k_b = q_b + (size_t)S_ * H_ * HD_;
  __bf16* vt_b = k_b + (size_t)S_ * KV_ * HD_;

  // 1. hidden fp32 -> bf16
  cvt_bf16<<<dim3(2048), dim3(256), 0, stream>>>(hidden, hb, (int)((size_t)S_ * D_ / 4));
  // 2. w_qkv [D][NQK] fp32 -> [NQK][D] bf16
  wtrans<<<dim3(NQK / 32, D_ / 32), dim3(32, 8), 0, stream>>>(w_qkv, wT, D_, NQK);
  // 3. qkv = hidden x w_qkv
  gemm_bt<<<dim3(NQK / 256, S_ / 256), dim3(512), 0, stream>>>(hb, wT, qkv, S_, NQK, D_);
  // 4. RoPE -> q_b (scaled by log2e/sqrt(hd)), k_b
  rope_qk<<<dim3(S_), dim3(256), 0, stream>>>(qkv, cosT, sinT, q_b, k_b);
  // 5. V transpose -> vt_b
  v_trans<<<dim3(S_ / 32, HD_ / 32, KV_), dim3(32, 8), 0, stream>>>(qkv, vt_b);
  // 6. w_out [6144][6144] fp32 -> transposed bf16 (reuses R0)
  wtrans<<<dim3(D_ / 32, D_ / 32), dim3(32, 8), 0, stream>>>(w_out, wT, D_, D_);
  // 7. attention -> attn_out bf16 (reuses R1)
  attn<<<dim3(S_ / 32, H_), dim3(64), 0, stream>>>(q_b, k_b, vt_b, hb);
  // 8. out = attn_out x w_out
  gemm_bt<<<dim3(D_ / 256, S_ / 256), dim3(512), 0, stream>>>(hb, wT, out, S_, D_, D_);
}

// Round 5
// 843.919 us; speedup vs baseline: 1.3253x; 1.1734x over previous
//
#include <hip/hip_runtime.h>

// ---------------------------------------------------------------------------
// DbrxAttention on MI355X (gfx950): QKV GEMM -> RoPE -> causal GQA flash attn
// -> out GEMM.
// GEMMs: 256x256 tile, BK=64, dbuf LDS, 4-phase/K-tile schedule with counted
// vmcnt + raw barriers + XOR-8 LDS swizzle + setprio (T2/T3/T4/T5).
// Attention: 4-wave blocks, K/V LDS-staged (swizzled), swapped-QK^T 32x32x16,
// softmax fully in registers (exp2 domain).
// ---------------------------------------------------------------------------

#define S_   2048
#define D_   6144
#define H_   48
#define KV_  8
#define HD_  128
#define NQK  8192   // (H + 2*KV) * HD
#define REP  6      // H / KV

typedef __attribute__((ext_vector_type(8)))  __bf16 bf16x8;
typedef __attribute__((ext_vector_type(4)))  __bf16 bf16x4;
typedef __attribute__((ext_vector_type(2)))  __bf16 bf16x2;
typedef __attribute__((ext_vector_type(4)))  float  f32x4;
typedef __attribute__((ext_vector_type(16))) float  f32x16;
typedef __attribute__((ext_vector_type(4)))  float  float4v;

__device__ __forceinline__ void gl_lds16(const void* g, void* l) {
  __builtin_amdgcn_global_load_lds(
      (const __attribute__((address_space(1))) void*)g,
      (__attribute__((address_space(3))) void*)l, 16, 0, 0);
}

__device__ __forceinline__ unsigned pack2(float a, float b) {
  union { bf16x2 v; unsigned u; } x;
  x.v[0] = (__bf16)a; x.v[1] = (__bf16)b;
  return x.u;
}

// ---------------- fp32 -> bf16 elementwise convert (vector4) ---------------
__global__ __launch_bounds__(256) void cvt_bf16(const float* __restrict__ in,
                                                __bf16* __restrict__ out, int n4) {
  int stride = gridDim.x * 256;
  for (int i = blockIdx.x * 256 + threadIdx.x; i < n4; i += stride) {
    float4v v = ((const float4v*)in)[i];
    bf16x4 o;
    o[0] = (__bf16)v[0]; o[1] = (__bf16)v[1];
    o[2] = (__bf16)v[2]; o[3] = (__bf16)v[3];
    ((bf16x4*)out)[i] = o;
  }
}

// ------------- fp32 [K][N] -> bf16 [N][K] tiled transpose+convert ----------
__global__ __launch_bounds__(256) void wtrans(const float* __restrict__ src,
                                              __bf16* __restrict__ dst,
                                              int K, int N) {
  __shared__ float t[32][33];
  const int n0 = blockIdx.x * 32, k0 = blockIdx.y * 32;
  const int tx = threadIdx.x, ty = threadIdx.y;  // (32, 8)
#pragma unroll
  for (int r = 0; r < 4; ++r)
    t[ty + r * 8][tx] = src[(size_t)(k0 + ty + r * 8) * N + n0 + tx];
  __syncthreads();
#pragma unroll
  for (int r = 0; r < 4; ++r)
    dst[(size_t)(n0 + ty + r * 8) * K + k0 + tx] = (__bf16)t[tx][ty + r * 8];
}

// --------- C[M][N] f32 = A[M][K] bf16 * BT[N][K] bf16 (both row-major) -----
// 256x256 tile, BK=64, 512 threads = 8 waves (2M x 4N), per-wave 128x64.
// Double-buffered LDS; tile T+1 staged across the 4 phases of tile T
// (unit p: p0=A rows 0-255 j01, p1=A j23, p2=B j01, p3=B j23).
// vmcnt(2) once per K-tile at p==0 (after issuing T+2's first unit),
// confirming tile T+1 fully landed; 2 loads always stay in flight.
// XOR-8 swizzle: LDS pos (row, c') holds global chunk c'^(row&7); reads use
// chunk' = (kk*4+lg)^(lr&7) -> 8 dwords/bank per b128 (conflict-free).
__global__ __launch_bounds__(512, 2) void gemm_bt(const __bf16* __restrict__ A,
                                                  const __bf16* __restrict__ BT,
                                                  float* __restrict__ C,
                                                  int M, int N, int K) {
  __shared__ __align__(16) __bf16 As[2][256 * 64];
  __shared__ __align__(16) __bf16 Bs[2][256 * 64];
  const int tid = threadIdx.x;
  const int w = tid >> 6, l = tid & 63;
  const int lr = l & 15, lg = l >> 4;
  const int wm = w >> 2, wn = w & 3;
  const int nwg = gridDim.x * gridDim.y;
  int bid = blockIdx.y * gridDim.x + blockIdx.x;
  bid = (bid & 7) * (nwg >> 3) + (bid >> 3);   // bijective: nwg % 8 == 0
  const int m0 = (bid / gridDim.x) * 256, n0 = (bid % gridDim.x) * 256;
  const int nkt = K >> 6;

  auto stage_unit = [&](int T, int u) {
    const int buf = T & 1;
    const int k0 = T << 6;
    const __bf16* src = (u < 2) ? A : BT;
    const int base0 = (u < 2) ? m0 : n0;
    __bf16* dst = (u < 2) ? As[buf] : Bs[buf];
#pragma unroll
    for (int jj = 0; jj < 2; ++jj) {
      int j = (u & 1) * 2 + jj;
      int idx = j * 512 + tid;
      int row = idx >> 3;
      int c = (idx & 7) ^ (row & 7);           // pre-swizzled source chunk
      gl_lds16(src + (size_t)(base0 + row) * K + k0 + c * 8,
               dst + (size_t)(j * 512 + w * 64) * 8);
    }
  };

  f32x4 acc[8][4] = {};
#pragma unroll
  for (int u = 0; u < 4; ++u) stage_unit(0, u);  // prologue: tile 0

  for (int T = 0; T < nkt; ++T) {
    const int buf = T & 1;
    const __bf16* Ab = As[buf];
    const __bf16* Bb = Bs[buf];
    bf16x8 bfr[4];
#pragma unroll
    for (int p = 0; p < 4; ++p) {
      if (T + 1 < nkt) stage_unit(T + 1, p);
      if (p == 0) {
        if (T + 1 < nkt) asm volatile("s_waitcnt vmcnt(2)" ::: "memory");
        else             asm volatile("s_waitcnt vmcnt(0)" ::: "memory");
      }
      __builtin_amdgcn_s_barrier();
      __builtin_amdgcn_sched_barrier(0);
      const int kk = p >> 1, mh = p & 1;
      if (mh == 0) {
#pragma unroll
        for (int n = 0; n < 4; ++n) {
          int row = wn * 64 + n * 16 + lr;
          bfr[n] = *(const bf16x8*)(Bb + (size_t)row * 64
                                    + (((kk * 4 + lg) ^ (lr & 7)) * 8));
        }
      }
      bf16x8 afr[4];
#pragma unroll
      for (int m = 0; m < 4; ++m) {
        int row = wm * 128 + (mh * 4 + m) * 16 + lr;
        afr[m] = *(const bf16x8*)(Ab + (size_t)row * 64
                                  + (((kk * 4 + lg) ^ (lr & 7)) * 8));
      }
      __builtin_amdgcn_s_setprio(1);
#pragma unroll
      for (int m = 0; m < 4; ++m)
#pragma unroll
        for (int n = 0; n < 4; ++n)
          acc[mh * 4 + m][n] = __builtin_amdgcn_mfma_f32_16x16x32_bf16(
              afr[m], bfr[n], acc[mh * 4 + m][n], 0, 0, 0);
      __builtin_amdgcn_s_setprio(0);
      __builtin_amdgcn_sched_barrier(0);
      __builtin_amdgcn_s_barrier();
    }
  }
  // C/D layout (m89-verified): col = lane&15, row = (lane>>4)*4 + j
#pragma unroll
  for (int m = 0; m < 8; ++m)
#pragma unroll
    for (int n = 0; n < 4; ++n)
#pragma unroll
      for (int j = 0; j < 4; ++j) {
        int row = m0 + wm * 128 + m * 16 + lg * 4 + j;
        int col = n0 + wn * 64 + n * 16 + lr;
        C[(size_t)row * N + col] = acc[m][n][j];
      }
}

// ------ RoPE on Q (scaled by log2(e)/sqrt(HD)) and K, fp32 -> bf16 ---------
__global__ __launch_bounds__(256) void rope_qk(const float* __restrict__ qkv,
                                               const float* __restrict__ cosT,
                                               const float* __restrict__ sinT,
                                               __bf16* __restrict__ Qo,
                                               __bf16* __restrict__ Ko) {
  const int s = blockIdx.x;
  const float* base = qkv + (size_t)s * NQK;
  const float* ct = cosT + s * HD_;
  const float* st = sinT + s * HD_;
  const float scale = 0.1275174313f;  // (1/sqrt(128)) * log2(e)
  for (int idx = threadIdx.x; idx < H_ * HD_; idx += 256) {
    int h = idx >> 7, d = idx & 127;
    float x = base[idx];
    float r = (d < 64) ? -base[idx + 64] : base[idx - 64];
    Qo[((size_t)s * H_ + h) * HD_ + d] = (__bf16)((x * ct[d] + r * st[d]) * scale);
  }
  for (int idx = threadIdx.x; idx < KV_ * HD_; idx += 256) {
    int h = idx >> 7, d = idx & 127;
    float x = base[H_ * HD_ + idx];
    float r = (d < 64) ? -base[H_ * HD_ + idx + 64] : base[H_ * HD_ + idx - 64];
    Ko[((size_t)s * KV_ + h) * HD_ + d] = (__bf16)(x * ct[d] + r * st[d]);
  }
}

// -------- V transpose: qkv[s][7168 + h*128 + d] f32 -> Vt[h][d][s] bf16 ----
__global__ __launch_bounds__(256) void v_trans(const float* __restrict__ qkv,
                                               __bf16* __restrict__ Vt) {
  __shared__ float t[32][33];
  const int s0 = blockIdx.x * 32, d0 = blockIdx.y * 32, h = blockIdx.z;
  const int tx = threadIdx.x, ty = threadIdx.y;  // (32, 8)
#pragma unroll
  for (int r = 0; r < 4; ++r)
    t[ty + r * 8][tx] = qkv[(size_t)(s0 + ty + r * 8) * NQK + (H_ + KV_) * HD_ + h * HD_ + d0 + tx];
  __syncthreads();
#pragma unroll
  for (int r = 0; r < 4; ++r)
    Vt[((size_t)h * HD_ + d0 + ty + r * 8) * S_ + s0 + tx] = (__bf16)t[tx][ty + r * 8];
}

// -------------------- causal GQA flash attention ---------------------------
// Grid (S/128, H), block 256 = 4 waves; wave w owns q-rows qb+w*32..+31.
// K tile [64][128] and V^T tile [128][64] staged in LDS (XOR-swizzled,
// global_load_lds issued early, drained by end-of-iter __syncthreads).
// Swapped QK^T: S^T[k][q] = mfma(A=Kfrag, B=Qfrag); lane (c,g) holds
// S[k=n*32+(r&3)+8*(r>>2)+4g][q=c].  Softmax in-lane + one shfl_xor(32).
// PV: O^T[d][q] = mfma(A=V^Tfrag, B=Pfrag), P exchanged via packed shfl.
__global__ __launch_bounds__(256, 2) void attn(const __bf16* __restrict__ Q,
                                               const __bf16* __restrict__ Kb,
                                               const __bf16* __restrict__ Vt,
                                               __bf16* __restrict__ O) {
  __shared__ __align__(16) __bf16 Ks[2][64 * 128];
  __shared__ __align__(16) __bf16 Vs[2][128 * 64];
  const int bx = blockIdx.x, h = blockIdx.y, kvh = h / REP;
  const int tid = threadIdx.x, w = tid >> 6, l = tid & 63;
  const int c = l & 31, g = l >> 5;
  const int qb = bx * 128;
  const int qrow = qb + w * 32 + c;
  const int tmax_w = (qb + w * 32 + 31) >> 6;  // last KV tile this wave needs
  const int NT = (qb >> 6) + 2;                // KV tiles staged by the block

  auto stage = [&](int t) {
    const int buf = t & 1;
    const int kbase = t << 6;
#pragma unroll
    for (int j = 0; j < 4; ++j) {              // K tile [64][128], 16 chunks/row
      int idx = j * 256 + tid;
      int row = idx >> 4, cc = (idx & 15) ^ (row & 15);
      gl_lds16(Kb + ((size_t)(kbase + row) * KV_ + kvh) * HD_ + cc * 8,
               Ks[buf] + (size_t)(j * 256 + w * 64) * 8);
    }
#pragma unroll
    for (int j = 0; j < 4; ++j) {              // V^T tile [128][64], 8 chunks/row
      int idx = j * 256 + tid;
      int row = idx >> 3, cc = (idx & 7) ^ (row & 7);
      gl_lds16(Vt + (size_t)(kvh * HD_ + row) * S_ + kbase + cc * 8,
               Vs[buf] + (size_t)(j * 256 + w * 64) * 8);
    }
  };

  bf16x8 qf[8];
  const __bf16* qp = Q + ((size_t)qrow * H_ + h) * HD_ + g * 8;
#pragma unroll
  for (int st = 0; st < 8; ++st) qf[st] = *(const bf16x8*)(qp + st * 16);

  f32x16 o[4] = {};
  float m = -1e30f, lsum = 0.f;

  stage(0);
  __syncthreads();
  for (int t = 0; t < NT; ++t) {
    const int buf = t & 1;
    if (t + 1 < NT) stage(t + 1);              // early issue; lands under compute
    if (t <= tmax_w) {
      const int kbase = t << 6;
      f32x16 s0 = {}, s1 = {};
      __builtin_amdgcn_s_setprio(1);
#pragma unroll
      for (int st = 0; st < 8; ++st) {
        int ch = ((st * 2 + g) ^ (c & 15)) * 8;
        bf16x8 k0 = *(const bf16x8*)(Ks[buf] + (size_t)c * 128 + ch);
        bf16x8 k1 = *(const bf16x8*)(Ks[buf] + (size_t)(32 + c) * 128 + ch);
        s0 = __builtin_amdgcn_mfma_f32_32x32x16_bf16(k0, qf[st], s0, 0, 0, 0);
        s1 = __builtin_amdgcn_mfma_f32_32x32x16_bf16(k1, qf[st], s1, 0, 0, 0);
      }
      __builtin_amdgcn_s_setprio(0);
      if (t == tmax_w) {                       // only last tile crosses diagonal
#pragma unroll
        for (int r = 0; r < 16; ++r) {
          int krow = (r & 3) + 8 * (r >> 2) + 4 * g;
          if (kbase + krow > qrow)      s0[r] = -1e30f;
          if (kbase + 32 + krow > qrow) s1[r] = -1e30f;
        }
      }
      // online softmax (exp2 domain)
      float mj = s0[0];
#pragma unroll
      for (int r = 1; r < 16; ++r) mj = fmaxf(mj, s0[r]);
#pragma unroll
      for (int r = 0; r < 16; ++r) mj = fmaxf(mj, s1[r]);
      mj = fmaxf(mj, __shfl_xor(mj, 32));
      float mnew = fmaxf(m, mj);
      float sc = __builtin_amdgcn_exp2f(m - mnew);
      float rs = 0.f;
      float p0[16], p1[16];
#pragma unroll
      for (int r = 0; r < 16; ++r) { p0[r] = __builtin_amdgcn_exp2f(s0[r] - mnew); rs += p0[r]; }
#pragma unroll
      for (int r = 0; r < 16; ++r) { p1[r] = __builtin_amdgcn_exp2f(s1[r] - mnew); rs += p1[r]; }
      rs += __shfl_xor(rs, 32);
      lsum = lsum * sc + rs;
      m = mnew;
#pragma unroll
      for (int db = 0; db < 4; ++db)
#pragma unroll
        for (int r = 0; r < 16; ++r) o[db][r] *= sc;
      // pack P -> bf16, exchange halves with partner lane, build B-fragments
      unsigned bq[4][4];
#pragma unroll
      for (int n = 0; n < 2; ++n)
#pragma unroll
        for (int tq = 0; tq < 2; ++tq) {
          const float* pp = n ? p1 : p0;
          unsigned q0 = pack2(pp[8 * tq + 0], pp[8 * tq + 1]);
          unsigned q1 = pack2(pp[8 * tq + 2], pp[8 * tq + 3]);
          unsigned q2 = pack2(pp[8 * tq + 4], pp[8 * tq + 5]);
          unsigned q3 = pack2(pp[8 * tq + 6], pp[8 * tq + 7]);
          unsigned v0 = g ? q0 : q2;
          unsigned v1 = g ? q1 : q3;
          unsigned sh0 = (unsigned)__shfl_xor((int)v0, 32);
          unsigned sh1 = (unsigned)__shfl_xor((int)v1, 32);
          int s = n * 2 + tq;
          bq[s][0] = g ? sh0 : q0;
          bq[s][1] = g ? sh1 : q1;
          bq[s][2] = g ? q2 : sh0;
          bq[s][3] = g ? q3 : sh1;
        }
      __builtin_amdgcn_s_setprio(1);
#pragma unroll
      for (int s = 0; s < 4; ++s) {
        union { unsigned u[4]; bf16x8 v; } bb;
        bb.u[0] = bq[s][0]; bb.u[1] = bq[s][1]; bb.u[2] = bq[s][2]; bb.u[3] = bq[s][3];
#pragma unroll
        for (int db = 0; db < 4; ++db) {
          int ch = ((s * 2 + g) ^ (c & 7)) * 8;
          bf16x8 vfr = *(const bf16x8*)(Vs[buf] + (size_t)(db * 32 + c) * 64 + ch);
          o[db] = __builtin_amdgcn_mfma_f32_32x32x16_bf16(vfr, bb.v, o[db], 0, 0, 0);
        }
      }
      __builtin_amdgcn_s_setprio(0);
    }
    if (t + 1 < NT) __syncthreads();           // drains stage loads (vmcnt 0)
  }
  // store O^T[d][q=c] -> O[qrow][h*128 + d], d = db*32 + 8*rg + 4g + j
  float inv = 1.f / lsum;
#pragma unroll
  for (int db = 0; db < 4; ++db)
#pragma unroll
    for (int rg = 0; rg < 4; ++rg) {
      bf16x4 ov;
#pragma unroll
      for (int j = 0; j < 4; ++j) ov[j] = (__bf16)(o[db][rg * 4 + j] * inv);
      *(bf16x4*)(O + (size_t)qrow * D_ + h * HD_ + db * 32 + rg * 8 + g * 4) = ov;
    }
}

// ---------------------------------------------------------------------------
extern "C" void kernel_launch(void* const* d_in, const int* in_sizes, int n_in,
                              void* d_out, int out_size, void* d_ws, size_t ws_size,
                              hipStream_t stream) {
  const float* hidden = (const float*)d_in[0];
  const float* cosT   = (const float*)d_in[1];
  const float* sinT   = (const float*)d_in[2];
  const float* w_qkv  = (const float*)d_in[3];
  const float* w_out  = (const float*)d_in[4];
  float* out = (float*)d_out;
  char* ws = (char*)d_ws;

  // Workspace regions:
  // R0 [0, 100.7MB): wqkvT bf16 [8192][6144], reused for woutT after gemm1
  // R1: hidden bf16 [2048][6144], reused for attn_out bf16 after gemm1
  // R2: qkv fp32 [2048][8192]
  // R3: q bf16 [2048][48][128], k bf16 [2048][8][128], vT bf16 [8][128][2048]
  __bf16* wT  = (__bf16*)ws;
  __bf16* hb  = (__bf16*)(ws + 100663296);
  float*  qkv = (float*)(ws + 100663296 + 25165824);
  __bf16* q_b = (__bf16*)(ws + 100663296 + 25165824 + 67108864);
  __bf16* k_b = q_b + (size_t)S_ * H_ * HD_;
  __bf16* vt_b = k_b + (size_t)S_ * KV_ * HD_;

  // 1. hidden fp32 -> bf16
  cvt_bf16<<<dim3(2048), dim3(256), 0, stream>>>(hidden, hb, (int)((size_t)S_ * D_ / 4));
  // 2. w_qkv [D][NQK] fp32 -> [NQK][D] bf16
  wtrans<<<dim3(NQK / 32, D_ / 32), dim3(32, 8), 0, stream>>>(w_qkv, wT, D_, NQK);
  // 3. qkv = hidden x w_qkv
  gemm_bt<<<dim3(NQK / 256, S_ / 256), dim3(512), 0, stream>>>(hb, wT, qkv, S_, NQK, D_);
  // 4. RoPE -> q_b (scaled by log2e/sqrt(hd)), k_b
  rope_qk<<<dim3(S_), dim3(256), 0, stream>>>(qkv, cosT, sinT, q_b, k_b);
  // 5. V transpose -> vt_b
  v_trans<<<dim3(S_ / 32, HD_ / 32, KV_), dim3(32, 8), 0, stream>>>(qkv, vt_b);
  // 6. w_out [6144][6144] fp32 -> transposed bf16 (reuses R0)
  wtrans<<<dim3(D_ / 32, D_ / 32), dim3(32, 8), 0, stream>>>(w_out, wT, D_, D_);
  // 7. attention -> attn_out bf16 (reuses R1)
  attn<<<dim3(S_ / 128, H_), dim3(256), 0, stream>>>(q_b, k_b, vt_b, hb);
  // 8. out = attn_out x w_out
  gemm_bt<<<dim3(D_ / 256, S_ / 256), dim3(512), 0, stream>>>(hb, wT, out, S_, D_, D_);
}

// Round 6
// 713.000 us; speedup vs baseline: 1.5687x; 1.1836x over previous
//
#include <hip/hip_runtime.h>

// ---------------------------------------------------------------------------
// DbrxAttention on MI355X (gfx950): QKV GEMM -> RoPE -> causal GQA flash attn
// -> out GEMM.
// GEMMs: 256x256 tile, BK=64, dbuf LDS, 4-phase/K-tile schedule. Phase order
// = m201's: ds_read BEFORE barrier (latency hides under barrier convergence
// and other waves' MFMA), counted in-flight staging, vmcnt(0) only at the
// tile boundary (p3), XOR-8 swizzle, setprio.
// Attention: 4-wave blocks, K/V LDS-staged (swizzled), swapped-QK^T 32x32x16,
// softmax fully in registers (exp2 domain).
// ---------------------------------------------------------------------------

#define S_   2048
#define D_   6144
#define H_   48
#define KV_  8
#define HD_  128
#define NQK  8192   // (H + 2*KV) * HD
#define REP  6      // H / KV

typedef __attribute__((ext_vector_type(8)))  __bf16 bf16x8;
typedef __attribute__((ext_vector_type(4)))  __bf16 bf16x4;
typedef __attribute__((ext_vector_type(2)))  __bf16 bf16x2;
typedef __attribute__((ext_vector_type(4)))  float  f32x4;
typedef __attribute__((ext_vector_type(16))) float  f32x16;
typedef __attribute__((ext_vector_type(4)))  float  float4v;

__device__ __forceinline__ void gl_lds16(const void* g, void* l) {
  __builtin_amdgcn_global_load_lds(
      (const __attribute__((address_space(1))) void*)g,
      (__attribute__((address_space(3))) void*)l, 16, 0, 0);
}

__device__ __forceinline__ unsigned pack2(float a, float b) {
  union { bf16x2 v; unsigned u; } x;
  x.v[0] = (__bf16)a; x.v[1] = (__bf16)b;
  return x.u;
}

// ---------------- fp32 -> bf16 elementwise convert (vector4) ---------------
__global__ __launch_bounds__(256) void cvt_bf16(const float* __restrict__ in,
                                                __bf16* __restrict__ out, int n4) {
  int stride = gridDim.x * 256;
  for (int i = blockIdx.x * 256 + threadIdx.x; i < n4; i += stride) {
    float4v v = ((const float4v*)in)[i];
    bf16x4 o;
    o[0] = (__bf16)v[0]; o[1] = (__bf16)v[1];
    o[2] = (__bf16)v[2]; o[3] = (__bf16)v[3];
    ((bf16x4*)out)[i] = o;
  }
}

// ------------- fp32 [K][N] -> bf16 [N][K] tiled transpose+convert ----------
__global__ __launch_bounds__(256) void wtrans(const float* __restrict__ src,
                                              __bf16* __restrict__ dst,
                                              int K, int N) {
  __shared__ float t[32][33];
  const int n0 = blockIdx.x * 32, k0 = blockIdx.y * 32;
  const int tx = threadIdx.x, ty = threadIdx.y;  // (32, 8)
#pragma unroll
  for (int r = 0; r < 4; ++r)
    t[ty + r * 8][tx] = src[(size_t)(k0 + ty + r * 8) * N + n0 + tx];
  __syncthreads();
#pragma unroll
  for (int r = 0; r < 4; ++r)
    dst[(size_t)(n0 + ty + r * 8) * K + k0 + tx] = (__bf16)t[tx][ty + r * 8];
}

// --------- C[M][N] f32 = A[M][K] bf16 * BT[N][K] bf16 (both row-major) -----
// 256x256 tile, BK=64, 512 threads = 8 waves (2M x 4N), per-wave 128x64.
// Double-buffered LDS.  Per K-tile, 4 phases (p = kk*2 + mh); each phase:
//   [ds_read frags (pre-barrier) | p0: stage ALL of tile T+1 | p3: vmcnt(0)]
//   s_barrier; lgkmcnt(0); sched_barrier; setprio(1); 16 MFMA; setprio(0);
//   s_barrier.
// Race-freedom: reads of buf[T&1] are consumed before each phase's MFMA
// (lgkmcnt(0)); stage(T+2)->buf[T&1] is issued only after p3's closing
// barrier.  T+1 readiness: p3's vmcnt(0) (+2 barriers) precedes T+1 reads;
// staged loads get ~3 phases of slack so the drain is near-free.
// XOR-8 swizzle: LDS (row, c') holds global chunk c'^(row&7); reads use
// chunk' = (kk*4+lg)^(lr&7) -> conflict-free b128.
__global__ __launch_bounds__(512, 2) void gemm_bt(const __bf16* __restrict__ A,
                                                  const __bf16* __restrict__ BT,
                                                  float* __restrict__ C,
                                                  int M, int N, int K) {
  __shared__ __align__(16) __bf16 As[2][256 * 64];
  __shared__ __align__(16) __bf16 Bs[2][256 * 64];
  const int tid = threadIdx.x;
  const int w = tid >> 6, l = tid & 63;
  const int lr = l & 15, lg = l >> 4;
  const int wm = w >> 2, wn = w & 3;
  const int nwg = gridDim.x * gridDim.y;
  int bid = blockIdx.y * gridDim.x + blockIdx.x;
  bid = (bid & 7) * (nwg >> 3) + (bid >> 3);   // bijective: nwg % 8 == 0
  const int m0 = (bid / gridDim.x) * 256, n0 = (bid % gridDim.x) * 256;
  const int nkt = K >> 6;

  // unit u: u0 = A rows 0-127, u1 = A rows 128-255, u2 = B 0-127, u3 = B 128-255
  auto stage_unit = [&](int T, int u) {
    const int buf = T & 1;
    const int k0 = T << 6;
    const __bf16* src = (u < 2) ? A : BT;
    const int base0 = (u < 2) ? m0 : n0;
    __bf16* dst = (u < 2) ? As[buf] : Bs[buf];
#pragma unroll
    for (int jj = 0; jj < 2; ++jj) {
      int j = (u & 1) * 2 + jj;
      int idx = j * 512 + tid;
      int row = idx >> 3;
      int c = (idx & 7) ^ (row & 7);           // pre-swizzled source chunk
      gl_lds16(src + (size_t)(base0 + row) * K + k0 + c * 8,
               dst + (size_t)(j * 512 + w * 64) * 8);
    }
  };

  f32x4 acc[8][4] = {};
#pragma unroll
  for (int u = 0; u < 4; ++u) stage_unit(0, u);  // prologue: tile 0
  asm volatile("s_waitcnt vmcnt(0)" ::: "memory");
  __builtin_amdgcn_s_barrier();

  for (int T = 0; T < nkt; ++T) {
    const __bf16* Ab = As[T & 1];
    const __bf16* Bb = Bs[T & 1];
    bf16x8 bfr[4];
#pragma unroll
    for (int p = 0; p < 4; ++p) {
      const int kk = p >> 1, mh = p & 1;
      // 1. ds_read this phase's fragments (issued pre-barrier)
      bf16x8 afr[4];
#pragma unroll
      for (int m = 0; m < 4; ++m) {
        int row = wm * 128 + (mh * 4 + m) * 16 + lr;
        afr[m] = *(const bf16x8*)(Ab + (size_t)row * 64
                                  + (((kk * 4 + lg) ^ (lr & 7)) * 8));
      }
      if (mh == 0) {
#pragma unroll
        for (int n = 0; n < 4; ++n) {
          int row = wn * 64 + n * 16 + lr;
          bfr[n] = *(const bf16x8*)(Bb + (size_t)row * 64
                                    + (((kk * 4 + lg) ^ (lr & 7)) * 8));
        }
      }
      // 2. staging: all of tile T+1 at p0 (stays in flight across p0-p2)
      if (p == 0 && T + 1 < nkt) {
#pragma unroll
        for (int u = 0; u < 4; ++u) stage_unit(T + 1, u);
      }
      // 3. tile-boundary readiness: T+1 must be landed before its p0 reads
      if (p == 3 && T + 1 < nkt)
        asm volatile("s_waitcnt vmcnt(0)" ::: "memory");
      __builtin_amdgcn_s_barrier();
      asm volatile("s_waitcnt lgkmcnt(0)" ::: "memory");
      __builtin_amdgcn_sched_barrier(0);
      __builtin_amdgcn_s_setprio(1);
#pragma unroll
      for (int m = 0; m < 4; ++m)
#pragma unroll
        for (int n = 0; n < 4; ++n)
          acc[mh * 4 + m][n] = __builtin_amdgcn_mfma_f32_16x16x32_bf16(
              afr[m], bfr[n], acc[mh * 4 + m][n], 0, 0, 0);
      __builtin_amdgcn_s_setprio(0);
      __builtin_amdgcn_sched_barrier(0);
      __builtin_amdgcn_s_barrier();
    }
  }
  // C/D layout (m89-verified): col = lane&15, row = (lane>>4)*4 + j
#pragma unroll
  for (int m = 0; m < 8; ++m)
#pragma unroll
    for (int n = 0; n < 4; ++n)
#pragma unroll
      for (int j = 0; j < 4; ++j) {
        int row = m0 + wm * 128 + m * 16 + lg * 4 + j;
        int col = n0 + wn * 64 + n * 16 + lr;
        C[(size_t)row * N + col] = acc[m][n][j];
      }
}

// ------ RoPE on Q (scaled by log2(e)/sqrt(HD)) and K, fp32 -> bf16 ---------
__global__ __launch_bounds__(256) void rope_qk(const float* __restrict__ qkv,
                                               const float* __restrict__ cosT,
                                               const float* __restrict__ sinT,
                                               __bf16* __restrict__ Qo,
                                               __bf16* __restrict__ Ko) {
  const int s = blockIdx.x;
  const float* base = qkv + (size_t)s * NQK;
  const float* ct = cosT + s * HD_;
  const float* st = sinT + s * HD_;
  const float scale = 0.1275174313f;  // (1/sqrt(128)) * log2(e)
  for (int idx = threadIdx.x; idx < H_ * HD_; idx += 256) {
    int h = idx >> 7, d = idx & 127;
    float x = base[idx];
    float r = (d < 64) ? -base[idx + 64] : base[idx - 64];
    Qo[((size_t)s * H_ + h) * HD_ + d] = (__bf16)((x * ct[d] + r * st[d]) * scale);
  }
  for (int idx = threadIdx.x; idx < KV_ * HD_; idx += 256) {
    int h = idx >> 7, d = idx & 127;
    float x = base[H_ * HD_ + idx];
    float r = (d < 64) ? -base[H_ * HD_ + idx + 64] : base[H_ * HD_ + idx - 64];
    Ko[((size_t)s * KV_ + h) * HD_ + d] = (__bf16)(x * ct[d] + r * st[d]);
  }
}

// -------- V transpose: qkv[s][7168 + h*128 + d] f32 -> Vt[h][d][s] bf16 ----
__global__ __launch_bounds__(256) void v_trans(const float* __restrict__ qkv,
                                               __bf16* __restrict__ Vt) {
  __shared__ float t[32][33];
  const int s0 = blockIdx.x * 32, d0 = blockIdx.y * 32, h = blockIdx.z;
  const int tx = threadIdx.x, ty = threadIdx.y;  // (32, 8)
#pragma unroll
  for (int r = 0; r < 4; ++r)
    t[ty + r * 8][tx] = qkv[(size_t)(s0 + ty + r * 8) * NQK + (H_ + KV_) * HD_ + h * HD_ + d0 + tx];
  __syncthreads();
#pragma unroll
  for (int r = 0; r < 4; ++r)
    Vt[((size_t)h * HD_ + d0 + ty + r * 8) * S_ + s0 + tx] = (__bf16)t[tx][ty + r * 8];
}

// -------------------- causal GQA flash attention ---------------------------
// Grid (S/128, H), block 256 = 4 waves; wave w owns q-rows qb+w*32..+31.
// K tile [64][128] and V^T tile [128][64] staged in LDS (XOR-swizzled,
// global_load_lds issued early, drained by end-of-iter __syncthreads).
// Swapped QK^T: S^T[k][q] = mfma(A=Kfrag, B=Qfrag); lane (c,g) holds
// S[k=n*32+(r&3)+8*(r>>2)+4g][q=c].  Softmax in-lane + one shfl_xor(32).
// PV: O^T[d][q] = mfma(A=V^Tfrag, B=Pfrag), P exchanged via packed shfl.
__global__ __launch_bounds__(256, 2) void attn(const __bf16* __restrict__ Q,
                                               const __bf16* __restrict__ Kb,
                                               const __bf16* __restrict__ Vt,
                                               __bf16* __restrict__ O) {
  __shared__ __align__(16) __bf16 Ks[2][64 * 128];
  __shared__ __align__(16) __bf16 Vs[2][128 * 64];
  const int bx = blockIdx.x, h = blockIdx.y, kvh = h / REP;
  const int tid = threadIdx.x, w = tid >> 6, l = tid & 63;
  const int c = l & 31, g = l >> 5;
  const int qb = bx * 128;
  const int qrow = qb + w * 32 + c;
  const int tmax_w = (qb + w * 32 + 31) >> 6;  // last KV tile this wave needs
  const int NT = (qb >> 6) + 2;                // KV tiles staged by the block

  auto stage = [&](int t) {
    const int buf = t & 1;
    const int kbase = t << 6;
#pragma unroll
    for (int j = 0; j < 4; ++j) {              // K tile [64][128], 16 chunks/row
      int idx = j * 256 + tid;
      int row = idx >> 4, cc = (idx & 15) ^ (row & 15);
      gl_lds16(Kb + ((size_t)(kbase + row) * KV_ + kvh) * HD_ + cc * 8,
               Ks[buf] + (size_t)(j * 256 + w * 64) * 8);
    }
#pragma unroll
    for (int j = 0; j < 4; ++j) {              // V^T tile [128][64], 8 chunks/row
      int idx = j * 256 + tid;
      int row = idx >> 3, cc = (idx & 7) ^ (row & 7);
      gl_lds16(Vt + (size_t)(kvh * HD_ + row) * S_ + kbase + cc * 8,
               Vs[buf] + (size_t)(j * 256 + w * 64) * 8);
    }
  };

  bf16x8 qf[8];
  const __bf16* qp = Q + ((size_t)qrow * H_ + h) * HD_ + g * 8;
#pragma unroll
  for (int st = 0; st < 8; ++st) qf[st] = *(const bf16x8*)(qp + st * 16);

  f32x16 o[4] = {};
  float m = -1e30f, lsum = 0.f;

  stage(0);
  __syncthreads();
  for (int t = 0; t < NT; ++t) {
    const int buf = t & 1;
    if (t + 1 < NT) stage(t + 1);              // early issue; lands under compute
    if (t <= tmax_w) {
      const int kbase = t << 6;
      f32x16 s0 = {}, s1 = {};
      __builtin_amdgcn_s_setprio(1);
#pragma unroll
      for (int st = 0; st < 8; ++st) {
        int ch = ((st * 2 + g) ^ (c & 15)) * 8;
        bf16x8 k0 = *(const bf16x8*)(Ks[buf] + (size_t)c * 128 + ch);
        bf16x8 k1 = *(const bf16x8*)(Ks[buf] + (size_t)(32 + c) * 128 + ch);
        s0 = __builtin_amdgcn_mfma_f32_32x32x16_bf16(k0, qf[st], s0, 0, 0, 0);
        s1 = __builtin_amdgcn_mfma_f32_32x32x16_bf16(k1, qf[st], s1, 0, 0, 0);
      }
      __builtin_amdgcn_s_setprio(0);
      if (t == tmax_w) {                       // only last tile crosses diagonal
#pragma unroll
        for (int r = 0; r < 16; ++r) {
          int krow = (r & 3) + 8 * (r >> 2) + 4 * g;
          if (kbase + krow > qrow)      s0[r] = -1e30f;
          if (kbase + 32 + krow > qrow) s1[r] = -1e30f;
        }
      }
      // online softmax (exp2 domain)
      float mj = s0[0];
#pragma unroll
      for (int r = 1; r < 16; ++r) mj = fmaxf(mj, s0[r]);
#pragma unroll
      for (int r = 0; r < 16; ++r) mj = fmaxf(mj, s1[r]);
      mj = fmaxf(mj, __shfl_xor(mj, 32));
      float mnew = fmaxf(m, mj);
      float sc = __builtin_amdgcn_exp2f(m - mnew);
      float rs = 0.f;
      float p0[16], p1[16];
#pragma unroll
      for (int r = 0; r < 16; ++r) { p0[r] = __builtin_amdgcn_exp2f(s0[r] - mnew); rs += p0[r]; }
#pragma unroll
      for (int r = 0; r < 16; ++r) { p1[r] = __builtin_amdgcn_exp2f(s1[r] - mnew); rs += p1[r]; }
      rs += __shfl_xor(rs, 32);
      lsum = lsum * sc + rs;
      m = mnew;
#pragma unroll
      for (int db = 0; db < 4; ++db)
#pragma unroll
        for (int r = 0; r < 16; ++r) o[db][r] *= sc;
      // pack P -> bf16, exchange halves with partner lane, build B-fragments
      unsigned bq[4][4];
#pragma unroll
      for (int n = 0; n < 2; ++n)
#pragma unroll
        for (int tq = 0; tq < 2; ++tq) {
          const float* pp = n ? p1 : p0;
          unsigned q0 = pack2(pp[8 * tq + 0], pp[8 * tq + 1]);
          unsigned q1 = pack2(pp[8 * tq + 2], pp[8 * tq + 3]);
          unsigned q2 = pack2(pp[8 * tq + 4], pp[8 * tq + 5]);
          unsigned q3 = pack2(pp[8 * tq + 6], pp[8 * tq + 7]);
          unsigned v0 = g ? q0 : q2;
          unsigned v1 = g ? q1 : q3;
          unsigned sh0 = (unsigned)__shfl_xor((int)v0, 32);
          unsigned sh1 = (unsigned)__shfl_xor((int)v1, 32);
          int s = n * 2 + tq;
          bq[s][0] = g ? sh0 : q0;
          bq[s][1] = g ? sh1 : q1;
          bq[s][2] = g ? q2 : sh0;
          bq[s][3] = g ? q3 : sh1;
        }
      __builtin_amdgcn_s_setprio(1);
#pragma unroll
      for (int s = 0; s < 4; ++s) {
        union { unsigned u[4]; bf16x8 v; } bb;
        bb.u[0] = bq[s][0]; bb.u[1] = bq[s][1]; bb.u[2] = bq[s][2]; bb.u[3] = bq[s][3];
#pragma unroll
        for (int db = 0; db < 4; ++db) {
          int ch = ((s * 2 + g) ^ (c & 7)) * 8;
          bf16x8 vfr = *(const bf16x8*)(Vs[buf] + (size_t)(db * 32 + c) * 64 + ch);
          o[db] = __builtin_amdgcn_mfma_f32_32x32x16_bf16(vfr, bb.v, o[db], 0, 0, 0);
        }
      }
      __builtin_amdgcn_s_setprio(0);
    }
    if (t + 1 < NT) __syncthreads();           // drains stage loads (vmcnt 0)
  }
  // store O^T[d][q=c] -> O[qrow][h*128 + d], d = db*32 + 8*rg + 4g + j
  float inv = 1.f / lsum;
#pragma unroll
  for (int db = 0; db < 4; ++db)
#pragma unroll
    for (int rg = 0; rg < 4; ++rg) {
      bf16x4 ov;
#pragma unroll
      for (int j = 0; j < 4; ++j) ov[j] = (__bf16)(o[db][rg * 4 + j] * inv);
      *(bf16x4*)(O + (size_t)qrow * D_ + h * HD_ + db * 32 + rg * 8 + g * 4) = ov;
    }
}

// ---------------------------------------------------------------------------
extern "C" void kernel_launch(void* const* d_in, const int* in_sizes, int n_in,
                              void* d_out, int out_size, void* d_ws, size_t ws_size,
                              hipStream_t stream) {
  const float* hidden = (const float*)d_in[0];
  const float* cosT   = (const float*)d_in[1];
  const float* sinT   = (const float*)d_in[2];
  const float* w_qkv  = (const float*)d_in[3];
  const float* w_out  = (const float*)d_in[4];
  float* out = (float*)d_out;
  char* ws = (char*)d_ws;

  // Workspace regions:
  // R0 [0, 100.7MB): wqkvT bf16 [8192][6144], reused for woutT after gemm1
  // R1: hidden bf16 [2048][6144], reused for attn_out bf16 after gemm1
  // R2: qkv fp32 [2048][8192]
  // R3: q bf16 [2048][48][128], k bf16 [2048][8][128], vT bf16 [8][128][2048]
  __bf16* wT  = (__bf16*)ws;
  __bf16* hb  = (__bf16*)(ws + 100663296);
  float*  qkv = (float*)(ws + 100663296 + 25165824);
  __bf16* q_b = (__bf16*)(ws + 100663296 + 25165824 + 67108864);
  __bf16* k_b = q_b + (size_t)S_ * H_ * HD_;
  __bf16* vt_b = k_b + (size_t)S_ * KV_ * HD_;

  // 1. hidden fp32 -> bf16
  cvt_bf16<<<dim3(2048), dim3(256), 0, stream>>>(hidden, hb, (int)((size_t)S_ * D_ / 4));
  // 2. w_qkv [D][NQK] fp32 -> [NQK][D] bf16
  wtrans<<<dim3(NQK / 32, D_ / 32), dim3(32, 8), 0, stream>>>(w_qkv, wT, D_, NQK);
  // 3. qkv = hidden x w_qkv
  gemm_bt<<<dim3(NQK / 256, S_ / 256), dim3(512), 0, stream>>>(hb, wT, qkv, S_, NQK, D_);
  // 4. RoPE -> q_b (scaled by log2e/sqrt(hd)), k_b
  rope_qk<<<dim3(S_), dim3(256), 0, stream>>>(qkv, cosT, sinT, q_b, k_b);
  // 5. V transpose -> vt_b
  v_trans<<<dim3(S_ / 32, HD_ / 32, KV_), dim3(32, 8), 0, stream>>>(qkv, vt_b);
  // 6. w_out [6144][6144] fp32 -> transposed bf16 (reuses R0)
  wtrans<<<dim3(D_ / 32, D_ / 32), dim3(32, 8), 0, stream>>>(w_out, wT, D_, D_);
  // 7. attention -> attn_out bf16 (reuses R1)
  attn<<<dim3(S_ / 128, H_), dim3(256), 0, stream>>>(q_b, k_b, vt_b, hb);
  // 8. out = attn_out x w_out
  gemm_bt<<<dim3(D_ / 256, S_ / 256), dim3(512), 0, stream>>>(hb, wT, out, S_, D_, D_);
}